// Round 7
// baseline (71.754 us; speedup 1.0000x reference)
//
#include <hip/hip_runtime.h>

// x[256,1,58,58] -> conv5x5(64) -> maxpool2 -> conv5x5(128) -> linear(10)
//   -> out[256,23,23,10] f32
//
// R7: conv2 switched to 32x32x16 MFMA (2x operand-bytes/FLOP efficiency vs
// 16x16x32). 17 M-tiles x 32 rows, 4 N-tiles x 32 oc; 8 waves = 4 m-groups
// x 2 n-groups. xs row stride 136B (odd word-stride -> bank-floor A-reads,
// done as b64 pairs). B-frags from L2-resident w2d (vecmem pipe, 1.6 MB/CU).

typedef __attribute__((ext_vector_type(8))) short bf16x8;
typedef __attribute__((ext_vector_type(4))) float f32x4;
typedef __attribute__((ext_vector_type(16))) float f32x16;
typedef __attribute__((ext_vector_type(2))) unsigned int u32x2;
typedef __attribute__((ext_vector_type(4))) unsigned int u32x4;

#define MFMA16(a, b, c) __builtin_amdgcn_mfma_f32_16x16x32_bf16((a), (b), (c), 0, 0, 0)
#define MFMA32(a, b, c) __builtin_amdgcn_mfma_f32_32x32x16_bf16((a), (b), (c), 0, 0, 0)

static __device__ __forceinline__ unsigned short f2bf(float f) {
    unsigned u = __builtin_bit_cast(unsigned, f);
    u += 0x7FFFu + ((u >> 16) & 1u);   // RNE
    return (unsigned short)(u >> 16);
}

// ---- K0: w2[oc128][ic64][kk25] -> w2d fragment order for 32x32x16:
//   entry = kk*1024 + ks*256 + nt*64 + lane   (each entry = 8 bf16 = 16B)
//   holds A/B elems: oc = nt*32 + (lane&31), ic = ks*16 + (lane>>5)*8 + j
__global__ __launch_bounds__(256) void prep_w2d(
    const float* __restrict__ w2, unsigned short* __restrict__ w2d)
{
    int t = blockIdx.x * 256 + threadIdx.x;        // 25600 entries
    if (t >= 25600) return;
    const int lane = t & 63, nt = (t >> 6) & 3, ks = (t >> 8) & 3, kk = t >> 10;
    const int oc = nt * 32 + (lane & 31);
    const int ic0 = ks * 16 + (lane >> 5) * 8;
    unsigned pk[4];
#pragma unroll
    for (int h = 0; h < 4; ++h) {
        unsigned short lo = f2bf(w2[oc * 1600 + (ic0 + 2 * h) * 25 + kk]);
        unsigned short hi = f2bf(w2[oc * 1600 + (ic0 + 2 * h + 1) * 25 + kk]);
        pk[h] = (unsigned)lo | ((unsigned)hi << 16);
    }
    u32x4 v; v.x = pk[0]; v.y = pk[1]; v.z = pk[2]; v.w = pk[3];
    *(u32x4*)(w2d + (size_t)t * 8) = v;
}

// LDS map (152320 B):
//   conv phase: xs  [0, 99144)        729 pixel rows x 136B (64 bf16 + 8B pad)
//               xbf [99144, 105872)   58x58 input as bf16
//               w1t [105872, 109968)  [k32][oc64] bf16
//   epilogue:   econ[0, 147968)       544 sp rows x 272B
//   always:     lwT [147968, 152320)  16 o rows x 272B
#define XS_STR   136
#define XBF_OFF  99144
#define W1T_OFF  105872
#define ECON_STR 272
#define LWT_OFF  147968
#define LDS_TOT  152320

__global__ __launch_bounds__(512, 2) void fused_net(
    const float* __restrict__ x, const float* __restrict__ w1,
    const unsigned short* __restrict__ w2d,
    const float* __restrict__ lw, const float* __restrict__ lb,
    float* __restrict__ out)
{
    extern __shared__ char lds[];
    unsigned short* xbf = (unsigned short*)(lds + XBF_OFF);
    unsigned short* w1t = (unsigned short*)(lds + W1T_OFF);
    const int b = blockIdx.x, tid = threadIdx.x;
    const int lane = tid & 63, w = tid >> 6;        // 8 waves
    const int l16 = lane & 15, kg = lane >> 4;      // 16x16 frag coords
    const int l32 = lane & 31, kg2 = lane >> 5;     // 32x32 frag coords
    const int mgrp = w >> 1, ngrp = w & 1;

    // ---- stage x -> xbf (bf16), w1 -> w1t [k][oc], lw -> lwT ----
    const float4* xg = (const float4*)(x + b * 3364);
    for (int i = tid; i < 841; i += 512) {
        float4 v = xg[i];
        unsigned p0 = (unsigned)f2bf(v.x) | ((unsigned)f2bf(v.y) << 16);
        unsigned p1 = (unsigned)f2bf(v.z) | ((unsigned)f2bf(v.w) << 16);
        *(uint2*)(xbf + i * 4) = make_uint2(p0, p1);
    }
    for (int i = tid; i < 2048; i += 512) {
        int k = i >> 6, oc = i & 63;
        w1t[i] = (k < 25) ? f2bf(w1[oc * 25 + k]) : (unsigned short)0;
    }
    for (int i = tid; i < 2048; i += 512) {
        int o = i >> 7, cc = i & 127;
        float v = (o < 10) ? lw[o * 128 + cc] : 0.f;
        *(unsigned short*)(lds + LWT_OFF + o * 272 + cc * 2) = f2bf(v);
    }
    __syncthreads();

    // ================= conv1 + maxpool -> xs (16x16x32 MFMA) =================
    {
        int koff[8];
        unsigned kmsk[8];
#pragma unroll
        for (int j = 0; j < 8; ++j) {
            int k = kg * 8 + j;
            int kh = k / 5, kw = k - 5 * kh;
            koff[j] = (k < 25) ? (kh * 58 + kw) : 0;
            kmsk[j] = (k < 25) ? 0xFFFFu : 0u;
        }
        bf16x8 bfrag[4];
#pragma unroll
        for (int ot = 0; ot < 4; ++ot)
#pragma unroll
            for (int j = 0; j < 8; ++j)
                bfrag[ot][j] = (short)w1t[(kg * 8 + j) * 64 + ot * 16 + l16];

        const f32x4 zero4 = {0.f, 0.f, 0.f, 0.f};
        for (int t = w; t < 183; t += 8) {
            int p = t * 4 + (l16 >> 2);
            if (p > 728) p = 728;
            const int q = l16 & 3;
            const int ph = p / 27, pw = p - 27 * ph;
            const int base = (2 * ph + (q >> 1)) * 58 + 2 * pw + (q & 1);
            bf16x8 afrag;
#pragma unroll
            for (int j = 0; j < 8; ++j)
                afrag[j] = (short)(xbf[base + koff[j]] & kmsk[j]);
            f32x4 acc1[4];
#pragma unroll
            for (int ot = 0; ot < 4; ++ot)
                acc1[ot] = MFMA16(afrag, bfrag[ot], zero4);
            const int pout = t * 4 + kg;
            if (pout < 729) {
#pragma unroll
                for (int ot = 0; ot < 4; ++ot) {
                    float m = fmaxf(fmaxf(acc1[ot][0], acc1[ot][1]),
                                    fmaxf(acc1[ot][2], acc1[ot][3]));
                    *(unsigned short*)(lds + pout * XS_STR + (ot * 16 + l16) * 2)
                        = f2bf(m);
                }
            }
        }
    }
    __syncthreads();   // xs complete; conv1 scratch (xbf/w1t) now dead

    // ============ conv2: 32x32x16, 17 M-tiles, 4 N-tiles ============
    // mgrp0: tiles 0-4 (5); mgrp m>=1: tiles 5+(m-1)*4 .. +3 (4).
    // tile 16 starts at row 497 (rows 497-528, partial overlap -> dup writes).
    const int mcnt = (mgrp == 0) ? 5 : 4;
    int ts[5], abase[5];
#pragma unroll
    for (int i = 0; i < 5; ++i) {
        int tile = (mgrp == 0) ? i : 5 + (mgrp - 1) * 4 + i;
        if (i >= mcnt) tile = mgrp;                  // unused slot, safe addr
        int tstart = tile * 32;
        if (tstart > 497) tstart = 497;
        ts[i] = tstart;
        const int sp = tstart + l32;
        const int oh = sp / 23, ow = sp - oh * 23;
        abase[i] = (oh * 27 + ow) * XS_STR + kg2 * 16;
    }

    f32x16 acc[5][2];
#pragma unroll
    for (int i = 0; i < 5; ++i)
#pragma unroll
        for (int j = 0; j < 2; ++j)
#pragma unroll
            for (int r = 0; r < 16; ++r) acc[i][j][r] = 0.f;

    for (int kk = 0; kk < 25; ++kk) {
        const int kh = kk / 5, kw = kk - 5 * kh;
        const int pixoff = (kh * 27 + kw) * XS_STR;
        // B-frags for this slice: [ks][ngrp-local nt], coalesced 1KB loads
        bf16x8 Bf[4][2];
#pragma unroll
        for (int ks = 0; ks < 4; ++ks)
#pragma unroll
            for (int j = 0; j < 2; ++j)
                Bf[ks][j] = *(const bf16x8*)(
                    w2d + ((size_t)kk * 1024 + ks * 256 +
                           (ngrp * 2 + j) * 64 + lane) * 8);
#pragma unroll
        for (int ks = 0; ks < 4; ++ks) {
#pragma unroll
            for (int i = 0; i < 5; ++i) {
                if (i < mcnt) {
                    const char* ap = lds + abase[i] + pixoff + ks * 32;
                    u32x2 lo = *(const u32x2*)(ap);
                    u32x2 hi = *(const u32x2*)(ap + 8);
                    u32x4 t4; t4.x = lo.x; t4.y = lo.y; t4.z = hi.x; t4.w = hi.y;
                    bf16x8 a = __builtin_bit_cast(bf16x8, t4);
                    acc[i][0] = MFMA32(a, Bf[ks][0], acc[i][0]);
                    acc[i][1] = MFMA32(a, Bf[ks][1], acc[i][1]);
                }
            }
        }
    }

    // ================= epilogue: econ bf16 + linear MFMA =================
    __syncthreads();   // all waves done reading xs before econ overwrites it
#pragma unroll
    for (int i = 0; i < 5; ++i) {
        if (i < mcnt) {
#pragma unroll
            for (int j = 0; j < 2; ++j) {
                const int col = (ngrp * 2 + j) * 32 + l32;
#pragma unroll
                for (int reg = 0; reg < 16; ++reg) {
                    const int row = (reg & 3) + 8 * (reg >> 2) + 4 * kg2;
                    *(unsigned short*)(lds + (ts[i] + row) * ECON_STR + col * 2)
                        = f2bf(acc[i][j][reg]);
                }
            }
        }
    }
    __syncthreads();

    const float lbv = (l16 < 10) ? lb[l16] : 0.f;
#pragma unroll
    for (int i = 0; i < 5; ++i) {
        const int t = w + 8 * i;
        if (t < 34) {
            f32x4 al = {0.f, 0.f, 0.f, 0.f};
            const char* arow = lds + (t * 16 + l16) * ECON_STR + kg * 16;
            const char* brow = lds + LWT_OFF + l16 * 272 + kg * 16;
#pragma unroll
            for (int ks = 0; ks < 4; ++ks) {
                bf16x8 av = *(const bf16x8*)(arow + ks * 64);
                bf16x8 bv = *(const bf16x8*)(brow + ks * 64);
                al = MFMA16(av, bv, al);
            }
            if (l16 < 10) {
#pragma unroll
                for (int r = 0; r < 4; ++r) {
                    int sp = t * 16 + kg * 4 + r;
                    if (sp < 529)
                        out[((size_t)b * 529 + sp) * 10 + l16] = al[r] + lbv;
                }
            }
        }
    }
}

extern "C" void kernel_launch(void* const* d_in, const int* in_sizes, int n_in,
                              void* d_out, int out_size, void* d_ws, size_t ws_size,
                              hipStream_t stream) {
    const float* x  = (const float*)d_in[0];
    const float* w1 = (const float*)d_in[1];
    const float* w2 = (const float*)d_in[2];
    const float* lw = (const float*)d_in[3];
    const float* lb = (const float*)d_in[4];
    float* out = (float*)d_out;

    unsigned short* w2d = (unsigned short*)d_ws;   // 400 KB fragment-ordered

    (void)hipFuncSetAttribute((const void*)fused_net,
                              hipFuncAttributeMaxDynamicSharedMemorySize,
                              LDS_TOT);

    prep_w2d<<<100, 256, 0, stream>>>(w2, w2d);
    fused_net<<<256, 512, LDS_TOT, stream>>>(x, w1, w2d, lw, lb, out);
}